// Round 7
// baseline (312.185 us; speedup 1.0000x reference)
//
#include <hip/hip_runtime.h>

// out = relu(concat(nf, prompt[bidx]) @ W1 + b1) @ W2 + b2
//   P2  = gp @ W1[512:] + b1               (tiny)
//   h   = relu(nf @ W1[:512] + P2[bidx])   (g1: 2-phase dbuf, fp32-A + bf16-B, BK=32)
//   out = h @ W2 + b2                      (g2: 2-phase dbuf, bf16 both, BK=32)

#define N_NODES 100000
#define NWG 3128                // 782 m-tiles * 4 n-tiles = 8 * 391 (bijective XCD chunks)

typedef __bf16 bf16x8 __attribute__((ext_vector_type(8)));
typedef float  f32x4  __attribute__((ext_vector_type(4)));
typedef unsigned short ushort_t;

__device__ __forceinline__ ushort_t f2bf(float f) {
  __bf16 b = (__bf16)f;
  return __builtin_bit_cast(unsigned short, b);
}

__device__ __forceinline__ bf16x8 cvt8(const float* p) {
  float4 x = *(const float4*)p;
  float4 y = *(const float4*)(p + 4);
  bf16x8 v;
  v[0] = (__bf16)x.x; v[1] = (__bf16)x.y; v[2] = (__bf16)x.z; v[3] = (__bf16)x.w;
  v[4] = (__bf16)y.x; v[5] = (__bf16)y.y; v[6] = (__bf16)y.z; v[7] = (__bf16)y.w;
  return v;
}

__device__ __forceinline__ bf16x8 cvt8v(float4 x, float4 y) {
  bf16x8 v;
  v[0] = (__bf16)x.x; v[1] = (__bf16)x.y; v[2] = (__bf16)x.z; v[3] = (__bf16)x.w;
  v[4] = (__bf16)y.x; v[5] = (__bf16)y.y; v[6] = (__bf16)y.z; v[7] = (__bf16)y.w;
  return v;
}

__device__ __forceinline__ void gload_lds16(const void* g, void* l) {
  __builtin_amdgcn_global_load_lds(
      (const __attribute__((address_space(1))) void*)g,
      (__attribute__((address_space(3))) void*)l, 16, 0, 0);
}

// ---------------- prep: weight transposes to bf16 ----------------
__global__ void prep_kernel(const float* __restrict__ W1, const float* __restrict__ W2,
                            ushort_t* __restrict__ W1T, ushort_t* __restrict__ W2T) {
  int i = blockIdx.x * 256 + threadIdx.x;
  if (i < 524288) {
    int n = i >> 10, k = i & 1023;
    W1T[i] = f2bf(W1[k * 512 + n]);             // W1T[n*1024+k]
  } else if (i < 786432) {
    int j = i - 524288;
    int n = j >> 9, k = j & 511;
    W2T[j] = f2bf(W2[k * 512 + n]);             // W2T[n*512+k]
  }
}

// ---------------- P2[g][n] = gp[g] @ W1[512:] + bias1 ----------------
__global__ __launch_bounds__(256, 4) void p2_kernel(
    const float* __restrict__ gp, const ushort_t* __restrict__ W1T,
    const float* __restrict__ bias1, float* __restrict__ P2) {
  const int tid = threadIdx.x, lane = tid & 63, wid = tid >> 6;
  const int lc = lane & 15, lr = lane >> 4;
  const int m0 = (blockIdx.x >> 1) * 32;
  const int col0 = (blockIdx.x & 1) * 256 + wid * 64;

  f32x4 acc[2][4];
#pragma unroll
  for (int i = 0; i < 2; ++i)
#pragma unroll
    for (int j = 0; j < 4; ++j) acc[i][j] = {0.f, 0.f, 0.f, 0.f};

  const float* a0 = gp + (size_t)(m0 + lc) * 512;
  const ushort_t* bb = W1T + (size_t)(col0 + lc) * 1024 + 512;

#pragma unroll 2
  for (int kt = 0; kt < 8; ++kt) {
    bf16x8 bfr[2][4];
#pragma unroll
    for (int kk = 0; kk < 2; ++kk)
#pragma unroll
      for (int j = 0; j < 4; ++j)
        bfr[kk][j] = *(const bf16x8*)(bb + (size_t)j * 16 * 1024 + kt * 64 + kk * 32 + lr * 8);
    bf16x8 af[2][2];
#pragma unroll
    for (int i = 0; i < 2; ++i)
#pragma unroll
      for (int kk = 0; kk < 2; ++kk)
        af[i][kk] = cvt8(a0 + (size_t)i * 16 * 512 + kt * 64 + kk * 32 + lr * 8);
#pragma unroll
    for (int kk = 0; kk < 2; ++kk)
#pragma unroll
      for (int i = 0; i < 2; ++i)
#pragma unroll
        for (int j = 0; j < 4; ++j)
          acc[i][j] = __builtin_amdgcn_mfma_f32_16x16x32_bf16(af[i][kk], bfr[kk][j], acc[i][j], 0, 0, 0);
  }

#pragma unroll
  for (int i = 0; i < 2; ++i)
#pragma unroll
    for (int r = 0; r < 4; ++r) {
      int row = m0 + i * 16 + lr * 4 + r;
#pragma unroll
      for (int j = 0; j < 4; ++j) {
        int col = col0 + j * 16 + lc;
        P2[(size_t)row * 512 + col] = acc[i][j][r] + bias1[col];
      }
    }
}

// ---------------- G1: h = relu(nf @ W1a + P2[bidx]); 2-phase dbuf, BK=32 ----------------
__global__ __launch_bounds__(256, 3) void g1_kernel(
    const float* __restrict__ nf, const int* __restrict__ bidx,
    const ushort_t* __restrict__ W1T, const float* __restrict__ P2,
    ushort_t* __restrict__ h) {
  __shared__ float    sAf[2][128 * 32];   // 2 x 16 KB fp32 A, chunk-swizzled (^row&7)
  __shared__ ushort_t sB[2][128 * 32];    // 2 x  8 KB bf16 B^T, chunk-swizzled (^row&3)

  const int tid = threadIdx.x, lane = tid & 63, wid = tid >> 6;
  const int tile = (blockIdx.x & 7) * 391 + (blockIdx.x >> 3);
  const int m0 = (tile >> 2) * 128, n0 = (tile & 3) * 128;

  // A: 4 chunks/thread (16B = 4 fp32); 8 chunks per 32-float row
  const float* pA[4]; int ldsA[4];
#pragma unroll
  for (int s = 0; s < 4; ++s) {
    int q = s * 256 + tid;
    int row = q >> 3;
    int cw = (q & 7) ^ (row & 7);
    int rowg = m0 + row; if (rowg > N_NODES - 1) rowg = N_NODES - 1;
    pA[s] = nf + (size_t)rowg * 512 + cw * 4;
    ldsA[s] = (s * 256 + wid * 64) * 4;
  }
  // B: 2 chunks/thread (16B = 8 bf16); 4 chunks per 32-elem row
  const ushort_t* pB[2]; int ldsB[2];
#pragma unroll
  for (int s = 0; s < 2; ++s) {
    int q = s * 256 + tid;
    int row = q >> 2;
    int cw = (q & 3) ^ (row & 3);
    pB[s] = W1T + (size_t)(n0 + row) * 1024 + cw * 8;
    ldsB[s] = (s * 256 + wid * 64) * 8;
  }

  f32x4 acc[4][4];
#pragma unroll
  for (int i = 0; i < 4; ++i)
#pragma unroll
    for (int j = 0; j < 4; ++j) acc[i][j] = {0.f, 0.f, 0.f, 0.f};

  const int wm = (wid >> 1) * 64, wn = (wid & 1) * 64;
  const int lr = lane >> 4, lc = lane & 15;

  // prologue: stage tile 0
#pragma unroll
  for (int s = 0; s < 4; ++s) { gload_lds16(pA[s], &sAf[0][ldsA[s]]); pA[s] += 32; }
#pragma unroll
  for (int s = 0; s < 2; ++s) { gload_lds16(pB[s], &sB[0][ldsB[s]]); pB[s] += 32; }
  __syncthreads();

#pragma unroll
  for (int kt = 0; kt < 16; ++kt) {
    const int cur = kt & 1;
    if (kt < 15) {   // stage next tile into other buffer (overlaps compute)
#pragma unroll
      for (int s = 0; s < 4; ++s) { gload_lds16(pA[s], &sAf[cur ^ 1][ldsA[s]]); pA[s] += 32; }
#pragma unroll
      for (int s = 0; s < 2; ++s) { gload_lds16(pB[s], &sB[cur ^ 1][ldsB[s]]); pB[s] += 32; }
    }
    // compute current tile: 16 MFMAs
    bf16x8 af[4], bfr[4];
#pragma unroll
    for (int i = 0; i < 4; ++i) {
      int row = wm + i * 16 + lc;
      int p0 = (lr * 2) ^ (row & 7);
      int p1 = (lr * 2 + 1) ^ (row & 7);
      float4 x = *(const float4*)&sAf[cur][row * 32 + p0 * 4];
      float4 y = *(const float4*)&sAf[cur][row * 32 + p1 * 4];
      af[i] = cvt8v(x, y);
    }
#pragma unroll
    for (int j = 0; j < 4; ++j) {
      int col = wn + j * 16 + lc;
      int pb = lr ^ (col & 3);
      bfr[j] = *(const bf16x8*)&sB[cur][col * 32 + pb * 8];
    }
#pragma unroll
    for (int i = 0; i < 4; ++i)
#pragma unroll
      for (int j = 0; j < 4; ++j)
        acc[i][j] = __builtin_amdgcn_mfma_f32_16x16x32_bf16(af[i], bfr[j], acc[i][j], 0, 0, 0);
    if (kt < 15) __syncthreads();   // drains next-tile stage; loads had whole compute to land
  }

  // epilogue: + P2[bidx[row]], relu, bf16 store
#pragma unroll
  for (int i = 0; i < 4; ++i) {
#pragma unroll
    for (int r = 0; r < 4; ++r) {
      int row = m0 + wm + i * 16 + lr * 4 + r;
      if (row < N_NODES) {
        int g = bidx[row];
        const float* p2r = P2 + (size_t)g * 512 + n0 + wn;
#pragma unroll
        for (int j = 0; j < 4; ++j) {
          float v = fmaxf(acc[i][j][r] + p2r[j * 16 + lc], 0.f);
          h[(size_t)row * 512 + n0 + wn + j * 16 + lc] = f2bf(v);
        }
      }
    }
  }
}

// ---------------- G2: out = h @ W2 + b2; 2-phase dbuf, BK=32, bf16 both ----------------
__global__ __launch_bounds__(256, 4) void g2_kernel(
    const ushort_t* __restrict__ h, const ushort_t* __restrict__ W2T,
    const float* __restrict__ bias2, float* __restrict__ out) {
  __shared__ ushort_t sA[2][128 * 32];   // 2 x 8 KB
  __shared__ ushort_t sB[2][128 * 32];   // 2 x 8 KB  (total 32 KB)

  const int tid = threadIdx.x, lane = tid & 63, wid = tid >> 6;
  const int tile = (blockIdx.x & 7) * 391 + (blockIdx.x >> 3);
  const int m0 = (tile >> 2) * 128, n0 = (tile & 3) * 128;

  const ushort_t* pA[2]; const ushort_t* pB[2]; int ldsW[2];
#pragma unroll
  for (int s = 0; s < 2; ++s) {
    int q = s * 256 + tid;
    int row = q >> 2;
    int cw = (q & 3) ^ (row & 3);
    int rowg = m0 + row; if (rowg > N_NODES - 1) rowg = N_NODES - 1;
    pA[s] = h + (size_t)rowg * 512 + cw * 8;
    pB[s] = W2T + (size_t)(n0 + row) * 512 + cw * 8;
    ldsW[s] = (s * 256 + wid * 64) * 8;
  }

  f32x4 acc[4][4];
#pragma unroll
  for (int i = 0; i < 4; ++i)
#pragma unroll
    for (int j = 0; j < 4; ++j) acc[i][j] = {0.f, 0.f, 0.f, 0.f};

  const int wm = (wid >> 1) * 64, wn = (wid & 1) * 64;
  const int lr = lane >> 4, lc = lane & 15;

  // prologue
#pragma unroll
  for (int s = 0; s < 2; ++s) {
    gload_lds16(pA[s], &sA[0][ldsW[s]]); pA[s] += 32;
    gload_lds16(pB[s], &sB[0][ldsW[s]]); pB[s] += 32;
  }
  __syncthreads();

#pragma unroll
  for (int kt = 0; kt < 16; ++kt) {
    const int cur = kt & 1;
    if (kt < 15) {
#pragma unroll
      for (int s = 0; s < 2; ++s) {
        gload_lds16(pA[s], &sA[cur ^ 1][ldsW[s]]); pA[s] += 32;
        gload_lds16(pB[s], &sB[cur ^ 1][ldsW[s]]); pB[s] += 32;
      }
    }
    bf16x8 af[4], bfr[4];
#pragma unroll
    for (int i = 0; i < 4; ++i) {
      int row = wm + i * 16 + lc;
      int pa = lr ^ (row & 3);
      af[i] = *(const bf16x8*)&sA[cur][row * 32 + pa * 8];
    }
#pragma unroll
    for (int j = 0; j < 4; ++j) {
      int col = wn + j * 16 + lc;
      int pb = lr ^ (col & 3);
      bfr[j] = *(const bf16x8*)&sB[cur][col * 32 + pb * 8];
    }
#pragma unroll
    for (int i = 0; i < 4; ++i)
#pragma unroll
      for (int j = 0; j < 4; ++j)
        acc[i][j] = __builtin_amdgcn_mfma_f32_16x16x32_bf16(af[i], bfr[j], acc[i][j], 0, 0, 0);
    if (kt < 15) __syncthreads();
  }

#pragma unroll
  for (int j = 0; j < 4; ++j) {
    int col = n0 + wn + j * 16 + lc;
    float bv = bias2[col];
#pragma unroll
    for (int i = 0; i < 4; ++i)
#pragma unroll
      for (int r = 0; r < 4; ++r) {
        int row = m0 + wm + i * 16 + lr * 4 + r;
        if (row < N_NODES) out[(size_t)row * 512 + col] = acc[i][j][r] + bv;
      }
  }
}

extern "C" void kernel_launch(void* const* d_in, const int* in_sizes, int n_in,
                              void* d_out, int out_size, void* d_ws, size_t ws_size,
                              hipStream_t stream) {
  const float* nf   = (const float*)d_in[0];   // [100000,512] f32
  const float* gp   = (const float*)d_in[1];   // [1024,512]  f32
  const int*   bidx = (const int*)d_in[2];     // [100000]    i32
  const float* W1   = (const float*)d_in[3];   // [1024,512]  f32
  const float* b1   = (const float*)d_in[4];   // [512]
  const float* W2   = (const float*)d_in[5];   // [512,512]   f32
  const float* b2   = (const float*)d_in[6];   // [512]
  float* out = (float*)d_out;

  char* ws = (char*)d_ws;
  ushort_t* W1T = (ushort_t*)ws;                  // 1,048,576 B
  ushort_t* W2T = (ushort_t*)(ws + 1048576);      //   524,288 B
  float*    P2  = (float*)   (ws + 1572864);      // 2,097,152 B
  ushort_t* hbf = (ushort_t*)(ws + 3670016);      // 102,400,000 B (total ~106 MB)

  prep_kernel<<<3072, 256, 0, stream>>>(W1, W2, W1T, W2T);
  p2_kernel<<<64, 256, 0, stream>>>(gp, W1T, b1, P2);
  g1_kernel<<<NWG, 256, 0, stream>>>(nf, bidx, W1T, P2, hbf);
  g2_kernel<<<NWG, 256, 0, stream>>>(hbf, W2T, b2, out);
}

// Round 8
// 276.501 us; speedup vs baseline: 1.1291x; 1.1291x over previous
//
#include <hip/hip_runtime.h>

// out = relu(concat(nf, prompt[bidx]) @ W1 + b1) @ W2 + b2
//   P2  = gp @ W1[512:] + b1               (tiny)
//   h   = relu(nf @ W1[:512] + P2[bidx])   (g1: reg-staged bf16 A + gload_lds B, BK=64)
//   out = h @ W2 + b2                      (g2: gload_lds both, BK=64)
// Round 8: occupancy experiment — 32 KB LDS + __launch_bounds__(256,4) on both GEMMs.

#define N_NODES 100000
#define NWG 3128                // 782 m-tiles * 4 n-tiles = 8 * 391 (bijective XCD chunks)

typedef __bf16 bf16x8 __attribute__((ext_vector_type(8)));
typedef float  f32x4  __attribute__((ext_vector_type(4)));
typedef unsigned short ushort_t;

__device__ __forceinline__ ushort_t f2bf(float f) {
  __bf16 b = (__bf16)f;
  return __builtin_bit_cast(unsigned short, b);
}

__device__ __forceinline__ bf16x8 cvt8(const float* p) {
  float4 x = *(const float4*)p;
  float4 y = *(const float4*)(p + 4);
  bf16x8 v;
  v[0] = (__bf16)x.x; v[1] = (__bf16)x.y; v[2] = (__bf16)x.z; v[3] = (__bf16)x.w;
  v[4] = (__bf16)y.x; v[5] = (__bf16)y.y; v[6] = (__bf16)y.z; v[7] = (__bf16)y.w;
  return v;
}

__device__ __forceinline__ bf16x8 cvt8v(float4 x, float4 y) {
  bf16x8 v;
  v[0] = (__bf16)x.x; v[1] = (__bf16)x.y; v[2] = (__bf16)x.z; v[3] = (__bf16)x.w;
  v[4] = (__bf16)y.x; v[5] = (__bf16)y.y; v[6] = (__bf16)y.z; v[7] = (__bf16)y.w;
  return v;
}

__device__ __forceinline__ void gload_lds16(const void* g, void* l) {
  __builtin_amdgcn_global_load_lds(
      (const __attribute__((address_space(1))) void*)g,
      (__attribute__((address_space(3))) void*)l, 16, 0, 0);
}

// ---------------- prep: weight transposes to bf16 ----------------
__global__ void prep_kernel(const float* __restrict__ W1, const float* __restrict__ W2,
                            ushort_t* __restrict__ W1T, ushort_t* __restrict__ W2T) {
  int i = blockIdx.x * 256 + threadIdx.x;
  if (i < 524288) {
    int n = i >> 10, k = i & 1023;
    W1T[i] = f2bf(W1[k * 512 + n]);             // W1T[n*1024+k]
  } else if (i < 786432) {
    int j = i - 524288;
    int n = j >> 9, k = j & 511;
    W2T[j] = f2bf(W2[k * 512 + n]);             // W2T[n*512+k]
  }
}

// ---------------- P2[g][n] = gp[g] @ W1[512:] + bias1 ----------------
__global__ __launch_bounds__(256, 4) void p2_kernel(
    const float* __restrict__ gp, const ushort_t* __restrict__ W1T,
    const float* __restrict__ bias1, float* __restrict__ P2) {
  const int tid = threadIdx.x, lane = tid & 63, wid = tid >> 6;
  const int lc = lane & 15, lr = lane >> 4;
  const int m0 = (blockIdx.x >> 1) * 32;
  const int col0 = (blockIdx.x & 1) * 256 + wid * 64;

  f32x4 acc[2][4];
#pragma unroll
  for (int i = 0; i < 2; ++i)
#pragma unroll
    for (int j = 0; j < 4; ++j) acc[i][j] = {0.f, 0.f, 0.f, 0.f};

  const float* a0 = gp + (size_t)(m0 + lc) * 512;
  const ushort_t* bb = W1T + (size_t)(col0 + lc) * 1024 + 512;

#pragma unroll 2
  for (int kt = 0; kt < 8; ++kt) {
    bf16x8 bfr[2][4];
#pragma unroll
    for (int kk = 0; kk < 2; ++kk)
#pragma unroll
      for (int j = 0; j < 4; ++j)
        bfr[kk][j] = *(const bf16x8*)(bb + (size_t)j * 16 * 1024 + kt * 64 + kk * 32 + lr * 8);
    bf16x8 af[2][2];
#pragma unroll
    for (int i = 0; i < 2; ++i)
#pragma unroll
      for (int kk = 0; kk < 2; ++kk)
        af[i][kk] = cvt8(a0 + (size_t)i * 16 * 512 + kt * 64 + kk * 32 + lr * 8);
#pragma unroll
    for (int kk = 0; kk < 2; ++kk)
#pragma unroll
      for (int i = 0; i < 2; ++i)
#pragma unroll
        for (int j = 0; j < 4; ++j)
          acc[i][j] = __builtin_amdgcn_mfma_f32_16x16x32_bf16(af[i][kk], bfr[kk][j], acc[i][j], 0, 0, 0);
  }

#pragma unroll
  for (int i = 0; i < 2; ++i)
#pragma unroll
    for (int r = 0; r < 4; ++r) {
      int row = m0 + i * 16 + lr * 4 + r;
#pragma unroll
      for (int j = 0; j < 4; ++j) {
        int col = col0 + j * 16 + lc;
        P2[(size_t)row * 512 + col] = acc[i][j][r] + bias1[col];
      }
    }
}

// ---------------- G1: h = relu(nf @ W1a + P2[bidx]); reg-staged bf16 A, BK=64 ----------------
__global__ __launch_bounds__(256, 4) void g1_kernel(
    const float* __restrict__ nf, const int* __restrict__ bidx,
    const ushort_t* __restrict__ W1T, const float* __restrict__ P2,
    ushort_t* __restrict__ h) {
  __shared__ ushort_t sA[128 * 64];   // 16 KB bf16 A, chunk-swizzled (^row&7)
  __shared__ ushort_t sB[128 * 64];   // 16 KB bf16 B^T, chunk-swizzled (^row&7)

  const int tid = threadIdx.x, lane = tid & 63, wid = tid >> 6;
  const int tile = (blockIdx.x & 7) * 391 + (blockIdx.x >> 3);   // chunked XCD swizzle
  const int m0 = (tile >> 2) * 128, n0 = (tile & 3) * 128;

  // A: 4 chunks/thread (8 bf16 elems each), reg-staged from fp32 with cvt
  const float* pAg[4]; int ldsA[4];
#pragma unroll
  for (int s = 0; s < 4; ++s) {
    int q = s * 256 + tid;              // chunk 0..1023; row = q>>3, phys slot = q&7
    int row = q >> 3;
    int cw = (q & 7) ^ (row & 7);       // logical k-chunk stored at this phys slot
    int rowg = m0 + row; if (rowg > N_NODES - 1) rowg = N_NODES - 1;
    pAg[s] = nf + (size_t)rowg * 512 + cw * 8;
    ldsA[s] = q * 8;                    // ushort index
  }
  // B: 4 chunks/thread via global_load_lds (wave-uniform dest)
  const ushort_t* pB[4]; int ldsB[4];
#pragma unroll
  for (int s = 0; s < 4; ++s) {
    int q = wid * 256 + s * 64 + lane;
    int row = q >> 3;
    int cw = (q & 7) ^ (row & 7);
    pB[s] = W1T + (size_t)(n0 + row) * 1024 + cw * 8;
    ldsB[s] = (wid * 256 + s * 64) * 8;
  }

  f32x4 acc[4][4];
#pragma unroll
  for (int i = 0; i < 4; ++i)
#pragma unroll
    for (int j = 0; j < 4; ++j) acc[i][j] = {0.f, 0.f, 0.f, 0.f};

  const int wm = (wid >> 1) * 64, wn = (wid & 1) * 64;
  const int lr = lane >> 4, lc = lane & 15;

  for (int kt = 0; kt < 8; ++kt) {
    // issue all A fp32 loads first (T14: loads early)
    float4 ax[4], ay[4];
#pragma unroll
    for (int s = 0; s < 4; ++s) {
      ax[s] = *(const float4*)(pAg[s]);
      ay[s] = *(const float4*)(pAg[s] + 4);
      pAg[s] += 64;
    }
    // B async global->LDS
#pragma unroll
    for (int s = 0; s < 4; ++s) { gload_lds16(pB[s], &sB[ldsB[s]]); pB[s] += 64; }
    // cvt + LDS write (waits A loads as values arrive)
#pragma unroll
    for (int s = 0; s < 4; ++s)
      *(bf16x8*)&sA[ldsA[s]] = cvt8v(ax[s], ay[s]);
    __syncthreads();

#pragma unroll
    for (int kk = 0; kk < 2; ++kk) {
      bf16x8 af[4], bfr[4];
#pragma unroll
      for (int i = 0; i < 4; ++i) {
        int row = wm + i * 16 + lc;
        int cp = (kk * 4 + lr) ^ (row & 7);
        af[i] = *(const bf16x8*)&sA[row * 64 + cp * 8];
      }
#pragma unroll
      for (int j = 0; j < 4; ++j) {
        int col = wn + j * 16 + lc;
        int cp = (kk * 4 + lr) ^ (col & 7);
        bfr[j] = *(const bf16x8*)&sB[col * 64 + cp * 8];
      }
#pragma unroll
      for (int i = 0; i < 4; ++i)
#pragma unroll
        for (int j = 0; j < 4; ++j)
          acc[i][j] = __builtin_amdgcn_mfma_f32_16x16x32_bf16(af[i], bfr[j], acc[i][j], 0, 0, 0);
    }
    __syncthreads();
  }

  // epilogue: + P2[bidx[row]], relu, bf16 store
#pragma unroll
  for (int i = 0; i < 4; ++i) {
#pragma unroll
    for (int r = 0; r < 4; ++r) {
      int row = m0 + wm + i * 16 + lr * 4 + r;
      if (row < N_NODES) {
        int g = bidx[row];
        const float* p2r = P2 + (size_t)g * 512 + n0 + wn;
#pragma unroll
        for (int j = 0; j < 4; ++j) {
          float v = fmaxf(acc[i][j][r] + p2r[j * 16 + lc], 0.f);
          h[(size_t)row * 512 + n0 + wn + j * 16 + lc] = f2bf(v);
        }
      }
    }
  }
}

// ---------------- G2: out = h @ W2 + b2 (f32); gload_lds both, BK=64 ----------------
__global__ __launch_bounds__(256, 4) void g2_kernel(
    const ushort_t* __restrict__ h, const ushort_t* __restrict__ W2T,
    const float* __restrict__ bias2, float* __restrict__ out) {
  __shared__ ushort_t sA[128 * 64];
  __shared__ ushort_t sB[128 * 64];

  const int tid = threadIdx.x, lane = tid & 63, wid = tid >> 6;
  const int tile = (blockIdx.x & 7) * 391 + (blockIdx.x >> 3);
  const int m0 = (tile >> 2) * 128, n0 = (tile & 3) * 128;

  const ushort_t* pA[4]; const ushort_t* pB[4]; int ldsW[4];
#pragma unroll
  for (int s = 0; s < 4; ++s) {
    int q = wid * 256 + s * 64 + lane;
    int row = q >> 3;
    int cw = (q & 7) ^ (row & 7);
    int rowg = m0 + row; if (rowg > N_NODES - 1) rowg = N_NODES - 1;
    pA[s] = h + (size_t)rowg * 512 + cw * 8;
    pB[s] = W2T + (size_t)(n0 + row) * 512 + cw * 8;
    ldsW[s] = (wid * 256 + s * 64) * 8;
  }

  f32x4 acc[4][4];
#pragma unroll
  for (int i = 0; i < 4; ++i)
#pragma unroll
    for (int j = 0; j < 4; ++j) acc[i][j] = {0.f, 0.f, 0.f, 0.f};

  const int wm = (wid >> 1) * 64, wn = (wid & 1) * 64;
  const int lr = lane >> 4, lc = lane & 15;

  for (int kt = 0; kt < 8; ++kt) {
#pragma unroll
    for (int s = 0; s < 4; ++s) {
      gload_lds16(pA[s], &sA[ldsW[s]]); pA[s] += 64;
      gload_lds16(pB[s], &sB[ldsW[s]]); pB[s] += 64;
    }
    __syncthreads();
#pragma unroll
    for (int kk = 0; kk < 2; ++kk) {
      bf16x8 af[4], bfr[4];
#pragma unroll
      for (int i = 0; i < 4; ++i) {
        int row = wm + i * 16 + lc;
        int cp = (kk * 4 + lr) ^ (row & 7);
        af[i] = *(const bf16x8*)&sA[row * 64 + cp * 8];
      }
#pragma unroll
      for (int j = 0; j < 4; ++j) {
        int col = wn + j * 16 + lc;
        int cp = (kk * 4 + lr) ^ (col & 7);
        bfr[j] = *(const bf16x8*)&sB[col * 64 + cp * 8];
      }
#pragma unroll
      for (int i = 0; i < 4; ++i)
#pragma unroll
        for (int j = 0; j < 4; ++j)
          acc[i][j] = __builtin_amdgcn_mfma_f32_16x16x32_bf16(af[i], bfr[j], acc[i][j], 0, 0, 0);
    }
    __syncthreads();
  }

#pragma unroll
  for (int j = 0; j < 4; ++j) {
    int col = n0 + wn + j * 16 + lc;
    float bv = bias2[col];
#pragma unroll
    for (int i = 0; i < 4; ++i)
#pragma unroll
      for (int r = 0; r < 4; ++r) {
        int row = m0 + wm + i * 16 + lr * 4 + r;
        if (row < N_NODES) out[(size_t)row * 512 + col] = acc[i][j][r] + bv;
      }
  }
}

extern "C" void kernel_launch(void* const* d_in, const int* in_sizes, int n_in,
                              void* d_out, int out_size, void* d_ws, size_t ws_size,
                              hipStream_t stream) {
  const float* nf   = (const float*)d_in[0];   // [100000,512] f32
  const float* gp   = (const float*)d_in[1];   // [1024,512]  f32
  const int*   bidx = (const int*)d_in[2];     // [100000]    i32
  const float* W1   = (const float*)d_in[3];   // [1024,512]  f32
  const float* b1   = (const float*)d_in[4];   // [512]
  const float* W2   = (const float*)d_in[5];   // [512,512]   f32
  const float* b2   = (const float*)d_in[6];   // [512]
  float* out = (float*)d_out;

  char* ws = (char*)d_ws;
  ushort_t* W1T = (ushort_t*)ws;                  // 1,048,576 B
  ushort_t* W2T = (ushort_t*)(ws + 1048576);      //   524,288 B
  float*    P2  = (float*)   (ws + 1572864);      // 2,097,152 B
  ushort_t* hbf = (ushort_t*)(ws + 3670016);      // 102,400,000 B (total ~106 MB)

  prep_kernel<<<3072, 256, 0, stream>>>(W1, W2, W1T, W2T);
  p2_kernel<<<64, 256, 0, stream>>>(gp, W1T, b1, P2);
  g1_kernel<<<NWG, 256, 0, stream>>>(nf, bidx, W1T, P2, hbf);
  g2_kernel<<<NWG, 256, 0, stream>>>(hbf, W2T, b2, out);
}